// Round 5
// baseline (1290.079 us; speedup 1.0000x reference)
//
#include <hip/hip_runtime.h>
#include <cstdint>
#include <cstddef>

#define H_ 64
#define W_ 64
#define T_ 32
#define CIN_ 16
#define COUT_ 64
#define K_ 432
#define TH_ 4
#define TW_ 16
#define WR_ 6          // window rows: 4 + 2 halo
#define WC_ 24         // padded window cols (18 used) -> perfect 2-way banks
#define WSZ_ (WR_ * WC_)     // 144
#define XTOT_ (CIN_ * WSZ_)  // 2304
#define NTHR_ 1024

// ---- prep: w_t[k][cout] f32, Gram d64[64][64] f64, inv64[64] f64 ----
__global__ void prep(const float* __restrict__ w, float* __restrict__ w_t,
                     double* __restrict__ d64, double* __restrict__ inv64) {
    const int i = blockIdx.x;   // cout row
    const int j = threadIdx.x;  // 0..63
    const float* wi = w + i * K_;
    const float* wj = w + j * K_;
    double acc = 0.0;
    for (int k = 0; k < K_; ++k) acc += (double)wi[k] * (double)wj[k];
    d64[i * 64 + j] = acc;
    if (i == j) inv64[i] = 1.0 / (acc + 1e-8);
    for (int k = j; k < K_; k += 64) w_t[k * 64 + i] = wi[k];
}

// ---- fused conv3d + spiking recurrence ----
__launch_bounds__(NTHR_, 4)
__global__ void fused_snn(const float* __restrict__ xg,
                          const float* __restrict__ beta_g, const float* __restrict__ bias_g,
                          const float* __restrict__ w_t, const double* __restrict__ d64,
                          const double* __restrict__ inv64, float* __restrict__ out) {
    __shared__ __align__(16) float x_win[2 * XTOT_];        // 18432 B, slot = z&1
    __shared__ __align__(16) double d_lds[64 * 65];         // 33280 B (padded rows)
    __shared__ unsigned int masks[2][64][2];                // 1024 B

    const int tid = threadIdx.x;
    const int b   = blockIdx.x;          // batch 0..3
    const int ty0 = blockIdx.y * TH_;
    const int tx0 = blockIdx.z * TW_;

    const int wv   = __builtin_amdgcn_readfirstlane(tid >> 6);  // wave 0..15
    const int lane = tid & 63;
    const int py   = lane >> 4;          // 0..3
    const int px   = lane & 15;          // 0..15
    const int c0   = wv * 4;             // wave owns couts [c0, c0+4)
    const int xoff = py * WC_ + px;

    for (int i = tid; i < 4096; i += NTHR_)
        d_lds[(i >> 6) * 65 + (i & 63)] = d64[i];
    if (tid < 128) masks[1][tid >> 1][tid & 1] = 0u;  // rbuf for t=0

    // stage slices z=0,1 into slots 0,1
    for (int z = 0; z < 2; ++z) {
        for (int i = tid; i < XTOT_; i += NTHR_) {
            int cin = i / WSZ_;
            int r2  = i - cin * WSZ_;
            int yy  = r2 / WC_;
            int xx  = r2 - yy * WC_;
            if (xx >= TW_ + 2) continue;        // pad cols never read
            int gy = ty0 - 1 + yy, gx = tx0 - 1 + xx;
            float v = 0.f;
            if (gy >= 0 && gy < H_ && gx >= 0 && gx < W_)
                v = xg[((size_t)(b * CIN_ + cin) * T_ + z) * (H_ * W_) + gy * W_ + gx];
            x_win[z * XTOT_ + i] = v;
        }
    }

    const double beta = (double)beta_g[0];
    const double omb  = 1.0 - beta;
    double inv_[4], bb[4];
#pragma unroll
    for (int ci = 0; ci < 4; ++ci) {
        inv_[ci] = inv64[c0 + ci];
        bb[ci]   = (double)bias_g[c0 + ci];
    }
    double mem[4] = {0.0, 0.0, 0.0, 0.0};
    double a0[4] = {}, a1[4] = {}, a2[4] = {};   // acc[t], acc[t+1], acc[t+2]

    // prefetch/staging index precompute (3 elems max per thread)
    int  pf_loff[3];
    size_t pf_goff[3];
    bool pf_use[3], pf_in[3];
#pragma unroll
    for (int r = 0; r < 3; ++r) {
        int i = tid + r * NTHR_;
        int cin = i / WSZ_;
        int r2  = i - cin * WSZ_;
        int yy  = r2 / WC_;
        int xx  = r2 - yy * WC_;
        pf_loff[r] = i;
        int gy = ty0 - 1 + yy, gx = tx0 - 1 + xx;
        bool ok = (i < XTOT_) && (xx < TW_ + 2);
        pf_use[r] = ok;
        pf_in[r]  = ok && gy >= 0 && gy < H_ && gx >= 0 && gx < W_;
        pf_goff[r] = (size_t)(b * CIN_ + cin) * (T_ * H_ * W_) + (size_t)gy * W_ + gx;
    }

    __syncthreads();   // staging of z=0,1 + d_lds visible

    // ---- prologue: slice z=0 contributes dz=1 -> a0, dz=0 -> a1 ----
    for (int g = 0; g < 8; ++g) {
        float cB[4] = {}, cC[4] = {};
#pragma unroll
        for (int cin2 = 0; cin2 < 2; ++cin2) {
            const int cin = g * 2 + cin2;
            const int base = cin * WSZ_ + xoff;
            float xv[9];
#pragma unroll
            for (int dy = 0; dy < 3; ++dy)
#pragma unroll
                for (int dx = 0; dx < 3; ++dx)
                    xv[dy * 3 + dx] = x_win[base + dy * WC_ + dx];
            const float* wr = w_t + cin * 27 * 64 + c0;
#pragma unroll
            for (int p = 0; p < 9; ++p) {           // dz=1 plane -> a0
                const float4 wv1 = *reinterpret_cast<const float4*>(wr + (9 + p) * 64);
                cB[0] = fmaf(wv1.x, xv[p], cB[0]); cB[1] = fmaf(wv1.y, xv[p], cB[1]);
                cB[2] = fmaf(wv1.z, xv[p], cB[2]); cB[3] = fmaf(wv1.w, xv[p], cB[3]);
            }
#pragma unroll
            for (int p = 0; p < 9; ++p) {           // dz=0 plane -> a1
                const float4 wv0 = *reinterpret_cast<const float4*>(wr + p * 64);
                cC[0] = fmaf(wv0.x, xv[p], cC[0]); cC[1] = fmaf(wv0.y, xv[p], cC[1]);
                cC[2] = fmaf(wv0.z, xv[p], cC[2]); cC[3] = fmaf(wv0.w, xv[p], cC[3]);
            }
        }
#pragma unroll
        for (int ci = 0; ci < 4; ++ci) {
            a0[ci] += (double)cB[ci];
            a1[ci] += (double)cC[ci];
        }
    }

    for (int t = 0; t < T_; ++t) {
        __syncthreads();   // A: prev staging writes + prev mask ORs visible
        if (tid < 128) masks[t & 1][tid >> 1][tid & 1] = 0u;  // clear wbuf

        // prefetch slice z=t+2 into regs (hidden under conv)
        float R[3];
        const int zp = t + 2;
        if (zp < T_) {
#pragma unroll
            for (int r = 0; r < 3; ++r) {
                R[r] = 0.f;
                if (pf_in[r]) R[r] = xg[pf_goff[r] + (size_t)zp * (H_ * W_)];
            }
        }

        // ---- conv: read ONLY slice z=t+1; apply its 3 dz-roles ----
        const int zc = t + 1;
        if (zc < T_) {
            const int sb = (zc & 1) * XTOT_ + xoff;
            for (int g = 0; g < 8; ++g) {
                float c2[4] = {}, c1[4] = {}, c0v[4] = {};
#pragma unroll
                for (int cin2 = 0; cin2 < 2; ++cin2) {
                    const int cin = g * 2 + cin2;
                    const int base = sb + cin * WSZ_;
                    float xv[9];
#pragma unroll
                    for (int dy = 0; dy < 3; ++dy)
#pragma unroll
                        for (int dx = 0; dx < 3; ++dx)
                            xv[dy * 3 + dx] = x_win[base + dy * WC_ + dx];
                    const float* wr = w_t + cin * 27 * 64 + c0;
#pragma unroll
                    for (int p = 0; p < 9; ++p) {   // dz=2 plane -> a0
                        const float4 wv = *reinterpret_cast<const float4*>(wr + (18 + p) * 64);
                        c2[0] = fmaf(wv.x, xv[p], c2[0]); c2[1] = fmaf(wv.y, xv[p], c2[1]);
                        c2[2] = fmaf(wv.z, xv[p], c2[2]); c2[3] = fmaf(wv.w, xv[p], c2[3]);
                    }
#pragma unroll
                    for (int p = 0; p < 9; ++p) {   // dz=1 plane -> a1
                        const float4 wv = *reinterpret_cast<const float4*>(wr + (9 + p) * 64);
                        c1[0] = fmaf(wv.x, xv[p], c1[0]); c1[1] = fmaf(wv.y, xv[p], c1[1]);
                        c1[2] = fmaf(wv.z, xv[p], c1[2]); c1[3] = fmaf(wv.w, xv[p], c1[3]);
                    }
#pragma unroll
                    for (int p = 0; p < 9; ++p) {   // dz=0 plane -> a2
                        const float4 wv = *reinterpret_cast<const float4*>(wr + p * 64);
                        c0v[0] = fmaf(wv.x, xv[p], c0v[0]); c0v[1] = fmaf(wv.y, xv[p], c0v[1]);
                        c0v[2] = fmaf(wv.z, xv[p], c0v[2]); c0v[3] = fmaf(wv.w, xv[p], c0v[3]);
                    }
                }
#pragma unroll
                for (int ci = 0; ci < 4; ++ci) {
                    a0[ci] += (double)c2[ci];
                    a1[ci] += (double)c1[ci];
                    a2[ci] += (double)c0v[ci];
                }
            }
        }

        // ---- rst from previous spikes (sparse via bitmask), fp64 d ----
        double rstv[4] = {0.0, 0.0, 0.0, 0.0};
        const int rb = (t + 1) & 1;
#pragma unroll
        for (int wrd = 0; wrd < 2; ++wrd) {
            unsigned int m = masks[rb][lane][wrd];
            while (m) {
                int bit = __ffs(m) - 1;
                m &= m - 1;
                const double* drow = &d_lds[(wrd * 32 + bit) * 65 + c0];
#pragma unroll
                for (int ci = 0; ci < 4; ++ci) rstv[ci] += drow[ci];
            }
        }

        // ---- membrane update (a0 = completed conv_out[t]), spike, store ----
        unsigned int nib = 0u;
        const size_t obase = ((size_t)(b * COUT_ + c0) * T_ + t) * (size_t)(H_ * W_)
                           + (size_t)(ty0 + py) * W_ + (tx0 + px);
#pragma unroll
        for (int ci = 0; ci < 4; ++ci) {
            mem[ci] = (mem[ci] - rstv[ci]) * beta + a0[ci] * omb;
            const double mthr = mem[ci] * inv_[ci] - bb[ci];
            const int s = mthr > 0.0 ? 1 : 0;
            out[obase + (size_t)ci * (T_ * H_ * W_)] = (float)s;
            nib |= (unsigned int)s << ci;
        }

        __syncthreads();   // B: clears done before ORs; conv reads done before writes
        if (nib) atomicOr(&masks[t & 1][lane][wv >> 3], nib << ((wv & 7) * 4));

        // write prefetched slice z=t+2 into slot (t+2)&1 (not read this iter)
        if (zp < T_) {
            const int so = (zp & 1) * XTOT_;
#pragma unroll
            for (int r = 0; r < 3; ++r)
                if (pf_use[r]) x_win[so + pf_loff[r]] = R[r];
        }

        // rotate accumulators (static indexing, registers only)
#pragma unroll
        for (int ci = 0; ci < 4; ++ci) {
            a0[ci] = a1[ci];
            a1[ci] = a2[ci];
            a2[ci] = 0.0;
        }
    }
}

extern "C" void kernel_launch(void* const* d_in, const int* in_sizes, int n_in,
                              void* d_out, int out_size, void* d_ws, size_t ws_size,
                              hipStream_t stream) {
    const float* x    = (const float*)d_in[0];
    const float* w    = (const float*)d_in[1];
    const float* beta = (const float*)d_in[2];
    const float* bias = (const float*)d_in[3];
    float* out = (float*)d_out;

    float*  w_t   = (float*)d_ws;                                   // 110592 B
    double* d64   = (double*)((char*)d_ws + 110592);                // 32768 B
    double* inv64 = (double*)((char*)d_ws + 110592 + 32768);        // 512 B

    prep<<<dim3(64), dim3(64), 0, stream>>>(w, w_t, d64, inv64);
    fused_snn<<<dim3(4, 16, 4), dim3(NTHR_), 0, stream>>>(x, beta, bias, w_t, d64, inv64, out);
}

// Round 6
// 534.078 us; speedup vs baseline: 2.4155x; 2.4155x over previous
//
#include <hip/hip_runtime.h>
#include <cstdint>
#include <cstddef>

#define H_ 64
#define W_ 64
#define T_ 32
#define CIN_ 16
#define COUT_ 64
#define K_ 432
#define TH_ 4
#define TW_ 16
#define WR_ 6          // window rows: 4 + 2 halo
#define WC_ 24         // padded window cols (18 used) -> perfect 2-way banks
#define WSZ_ (WR_ * WC_)     // 144
#define XTOT_ (CIN_ * WSZ_)  // 2304
#define NSLOT_ 4
#define NTHR_ 1024

// ---- prep: w_t[k][cout] f32, Gram d64[64][64] f64, inv64[64] f64 ----
__global__ void prep(const float* __restrict__ w, float* __restrict__ w_t,
                     double* __restrict__ d64, double* __restrict__ inv64) {
    const int i = blockIdx.x;   // cout row
    const int j = threadIdx.x;  // 0..63
    const float* wi = w + i * K_;
    const float* wj = w + j * K_;
    double acc = 0.0;
    for (int k = 0; k < K_; ++k) acc += (double)wi[k] * (double)wj[k];
    d64[i * 64 + j] = acc;
    if (i == j) inv64[i] = 1.0 / (acc + 1e-8);
    for (int k = j; k < K_; k += 64) w_t[k * 64 + i] = wi[k];
}

// ---- fused conv3d + spiking recurrence (R3 structure, padded window) ----
__launch_bounds__(NTHR_, 1)
__global__ void fused_snn(const float* __restrict__ xg,
                          const float* __restrict__ beta_g, const float* __restrict__ bias_g,
                          const float* __restrict__ w_t, const double* __restrict__ d64,
                          const double* __restrict__ inv64, float* __restrict__ out) {
    __shared__ __align__(16) float x_win[NSLOT_ * XTOT_];   // 36864 B
    __shared__ __align__(16) double d_lds[64 * 65];         // 33280 B (padded rows)
    __shared__ unsigned int masks[2][64][2];                // 1024 B

    const int tid = threadIdx.x;
    const int b   = blockIdx.x;          // batch 0..3
    const int ty0 = blockIdx.y * TH_;
    const int tx0 = blockIdx.z * TW_;

    const int wv   = __builtin_amdgcn_readfirstlane(tid >> 6);  // wave 0..15
    const int lane = tid & 63;
    const int py   = lane >> 4;          // 0..3
    const int px   = lane & 15;          // 0..15
    const int c0   = wv * 4;             // wave owns couts [c0, c0+4)
    const int xoff = py * WC_ + px;

    for (int i = tid; i < 4096; i += NTHR_)
        d_lds[(i >> 6) * 65 + (i & 63)] = d64[i];
    if (tid < 128) masks[1][tid >> 1][tid & 1] = 0u;  // rbuf for t=0

    // stage slices z=0,1 into slots 0,1
    for (int z = 0; z < 2; ++z) {
        for (int i = tid; i < XTOT_; i += NTHR_) {
            int cin = i / WSZ_;
            int r2  = i - cin * WSZ_;
            int yy  = r2 / WC_;
            int xx  = r2 - yy * WC_;
            if (xx >= TW_ + 2) continue;        // pad cols never read
            int gy = ty0 - 1 + yy, gx = tx0 - 1 + xx;
            float v = 0.f;
            if (gy >= 0 && gy < H_ && gx >= 0 && gx < W_)
                v = xg[((size_t)(b * CIN_ + cin) * T_ + z) * (H_ * W_) + gy * W_ + gx];
            x_win[z * XTOT_ + i] = v;
        }
    }

    const double beta = (double)beta_g[0];
    const double omb  = 1.0 - beta;
    double inv_[4], bb[4];
#pragma unroll
    for (int ci = 0; ci < 4; ++ci) {
        inv_[ci] = inv64[c0 + ci];
        bb[ci]   = (double)bias_g[c0 + ci];
    }
    double mem[4];
#pragma unroll
    for (int ci = 0; ci < 4; ++ci) mem[ci] = 0.0;

    // prefetch/staging index precompute (3 elems max per thread)
    int  pf_loff[3];
    size_t pf_goff[3];
    bool pf_use[3], pf_in[3];
#pragma unroll
    for (int r = 0; r < 3; ++r) {
        int i = tid + r * NTHR_;
        int cin = i / WSZ_;
        int r2  = i - cin * WSZ_;
        int yy  = r2 / WC_;
        int xx  = r2 - yy * WC_;
        pf_loff[r] = i;
        int gy = ty0 - 1 + yy, gx = tx0 - 1 + xx;
        bool ok = (i < XTOT_) && (xx < TW_ + 2);
        pf_use[r] = ok;
        pf_in[r]  = ok && gy >= 0 && gy < H_ && gx >= 0 && gx < W_;
        pf_goff[r] = (size_t)(b * CIN_ + cin) * (T_ * H_ * W_) + (size_t)gy * W_ + gx;
    }

    for (int t = 0; t < T_; ++t) {
        __syncthreads();   // A: prev LDS writes + prev mask ORs visible
        if (tid < 128) masks[t & 1][tid >> 1][tid & 1] = 0u;  // clear wbuf

        // prefetch slice z=t+2 into regs (hidden under conv)
        float R[3];
        const int zp = t + 2;
        if (zp < T_) {
#pragma unroll
            for (int r = 0; r < 3; ++r) {
                R[r] = 0.f;
                if (pf_in[r]) R[r] = xg[pf_goff[r] + (size_t)zp * (H_ * W_)];
            }
        }

        // ---- conv: fp32 products, per-cin fp64 accumulate (R3 schedule) ----
        double accd[4];
#pragma unroll
        for (int ci = 0; ci < 4; ++ci) accd[ci] = 0.0;

        int slot_[3]; bool zok[3];
#pragma unroll
        for (int dz = 0; dz < 3; ++dz) {
            int z = t - 1 + dz;
            zok[dz]  = (z >= 0 && z < T_);
            slot_[dz] = zok[dz] ? (z & 3) : 0;
        }

        for (int cin = 0; cin < CIN_; ++cin) {
            float cacc[4];
#pragma unroll
            for (int ci = 0; ci < 4; ++ci) cacc[ci] = 0.f;
#pragma unroll
            for (int dz = 0; dz < 3; ++dz) {
                if (!zok[dz]) continue;
                const float* xs = &x_win[slot_[dz] * XTOT_ + cin * WSZ_] + xoff;
                const float* wr = w_t + (cin * 27 + dz * 9) * 64 + c0;  // wave-uniform -> s_load
#pragma unroll
                for (int dy = 0; dy < 3; ++dy) {
                    const float xv0 = xs[dy * WC_ + 0];
                    const float xv1 = xs[dy * WC_ + 1];
                    const float xv2 = xs[dy * WC_ + 2];
                    const float4 w0 = *reinterpret_cast<const float4*>(wr + dy * 192);
                    const float4 w1 = *reinterpret_cast<const float4*>(wr + dy * 192 + 64);
                    const float4 w2 = *reinterpret_cast<const float4*>(wr + dy * 192 + 128);
                    cacc[0] = fmaf(w0.x, xv0, cacc[0]);
                    cacc[1] = fmaf(w0.y, xv0, cacc[1]);
                    cacc[2] = fmaf(w0.z, xv0, cacc[2]);
                    cacc[3] = fmaf(w0.w, xv0, cacc[3]);
                    cacc[0] = fmaf(w1.x, xv1, cacc[0]);
                    cacc[1] = fmaf(w1.y, xv1, cacc[1]);
                    cacc[2] = fmaf(w1.z, xv1, cacc[2]);
                    cacc[3] = fmaf(w1.w, xv1, cacc[3]);
                    cacc[0] = fmaf(w2.x, xv2, cacc[0]);
                    cacc[1] = fmaf(w2.y, xv2, cacc[1]);
                    cacc[2] = fmaf(w2.z, xv2, cacc[2]);
                    cacc[3] = fmaf(w2.w, xv2, cacc[3]);
                }
            }
#pragma unroll
            for (int ci = 0; ci < 4; ++ci) accd[ci] += (double)cacc[ci];
        }

        // ---- rst from previous spikes (sparse via bitmask), fp64 d ----
        double rstv[4];
#pragma unroll
        for (int ci = 0; ci < 4; ++ci) rstv[ci] = 0.0;
        const int rb = (t + 1) & 1;
#pragma unroll
        for (int wrd = 0; wrd < 2; ++wrd) {
            unsigned int m = masks[rb][lane][wrd];
            while (m) {
                int bit = __ffs(m) - 1;
                m &= m - 1;
                const double* drow = &d_lds[(wrd * 32 + bit) * 65 + c0];
#pragma unroll
                for (int ci = 0; ci < 4; ++ci) rstv[ci] += drow[ci];
            }
        }

        // ---- membrane update, spike, store ----
        unsigned int nib = 0u;
        const size_t obase = ((size_t)(b * COUT_ + c0) * T_ + t) * (size_t)(H_ * W_)
                           + (size_t)(ty0 + py) * W_ + (tx0 + px);
#pragma unroll
        for (int ci = 0; ci < 4; ++ci) {
            mem[ci] = (mem[ci] - rstv[ci]) * beta + accd[ci] * omb;
            const double mthr = mem[ci] * inv_[ci] - bb[ci];
            const int s = mthr > 0.0 ? 1 : 0;
            out[obase + (size_t)ci * (T_ * H_ * W_)] = (float)s;
            nib |= (unsigned int)s << ci;
        }

        __syncthreads();   // B: all clears + conv reads done before ORs / x writes
        if (nib) atomicOr(&masks[t & 1][lane][wv >> 3], nib << ((wv & 7) * 4));

        // write prefetched slice z=t+2 into slot (t+2)&3 (not read this iter)
        if (zp < T_) {
            const int so = (zp & 3) * XTOT_;
#pragma unroll
            for (int r = 0; r < 3; ++r)
                if (pf_use[r]) x_win[so + pf_loff[r]] = R[r];
        }
    }
}

extern "C" void kernel_launch(void* const* d_in, const int* in_sizes, int n_in,
                              void* d_out, int out_size, void* d_ws, size_t ws_size,
                              hipStream_t stream) {
    const float* x    = (const float*)d_in[0];
    const float* w    = (const float*)d_in[1];
    const float* beta = (const float*)d_in[2];
    const float* bias = (const float*)d_in[3];
    float* out = (float*)d_out;

    float*  w_t   = (float*)d_ws;                                   // 110592 B
    double* d64   = (double*)((char*)d_ws + 110592);                // 32768 B
    double* inv64 = (double*)((char*)d_ws + 110592 + 32768);        // 512 B

    prep<<<dim3(64), dim3(64), 0, stream>>>(w, w_t, d64, inv64);
    fused_snn<<<dim3(4, 16, 4), dim3(NTHR_), 0, stream>>>(x, beta, bias, w_t, d64, inv64, out);
}